// Round 1
// baseline (888.424 us; speedup 1.0000x reference)
//
#include <hip/hip_runtime.h>
#include <math.h>

constexpr float DELTA_ = 2.5f;

// ---------- small prep kernels ----------

__global__ __launch_bounds__(256) void k_tU(const float* __restrict__ Uw, float* __restrict__ UwT){
  int i = blockIdx.x*256 + threadIdx.x;            // i = (t*832 + k)*64 + o
  if (i >= 4*832*64) return;
  int o = i & 63;
  int k = (i >> 6) % 832;
  int t = (i >> 6) / 832;
  UwT[i] = Uw[(size_t)(t*64 + o)*832 + k];
}

__global__ __launch_bounds__(256) void k_tM(const float* __restrict__ Mx, float* __restrict__ MxT){
  int i = blockIdx.x*256 + threadIdx.x;            // i = k*256 + j
  if (i >= 256*256) return;
  int j = i & 255, k = i >> 8;
  MxT[i] = Mx[j*256 + k];
}

__global__ __launch_bounds__(256) void k_hist(const int* __restrict__ dstv, int* __restrict__ cnt, int E){
  int e = blockIdx.x*256 + threadIdx.x;
  if (e < E) atomicAdd(&cnt[dstv[e]], 1);
}

__global__ __launch_bounds__(256) void k_scan1(const int* __restrict__ cnt, int* __restrict__ offs,
                                               int* __restrict__ bsum, int N){
  __shared__ int lds[256];
  int i = threadIdx.x;
  int g = blockIdx.x*256 + i;
  int v = (g < N) ? cnt[g] : 0;
  int acc = v;
  lds[i] = acc; __syncthreads();
  for (int s = 1; s < 256; s <<= 1){
    int t = (i >= s) ? lds[i - s] : 0;
    __syncthreads();
    acc += t; lds[i] = acc;
    __syncthreads();
  }
  if (g < N) offs[g] = acc - v;                    // exclusive within block
  if (i == 255) bsum[blockIdx.x] = acc;
}

__global__ __launch_bounds__(256) void k_scan2(int* __restrict__ bsum, int NB){
  __shared__ int lds[256];
  int i = threadIdx.x;
  int v = (i < NB) ? bsum[i] : 0;
  int acc = v;
  lds[i] = acc; __syncthreads();
  for (int s = 1; s < 256; s <<= 1){
    int t = (i >= s) ? lds[i - s] : 0;
    __syncthreads();
    acc += t; lds[i] = acc;
    __syncthreads();
  }
  if (i < NB) bsum[i] = acc - v;                   // exclusive block offsets
}

__global__ __launch_bounds__(256) void k_scan3(int* __restrict__ offs, const int* __restrict__ bsum, int N, int E){
  int g = blockIdx.x*256 + threadIdx.x;
  if (g < N) offs[g] += bsum[blockIdx.x];
  if (g == 0) offs[N] = E;
}

__global__ __launch_bounds__(256) void k_fill(const int* __restrict__ dstv, const int* __restrict__ offs,
                                              int* __restrict__ cur, int* __restrict__ elist, int E){
  int e = blockIdx.x*256 + threadIdx.x;
  if (e < E){
    int d = dstv[e];
    elist[offs[d] + atomicAdd(&cur[d], 1)] = e;
  }
}

// ---------- A = W_src*h, B = W_dst*h + M_b (per node) ----------

__global__ __launch_bounds__(256) void k_ab(const float* __restrict__ nf, const float* __restrict__ Mw,
                                            const float* __restrict__ Mb,
                                            float* __restrict__ A, float* __restrict__ B, int N){
  int c = threadIdx.x;
  int t = __builtin_amdgcn_readfirstlane(threadIdx.x >> 6);
  float ws[64], wd[64];
  const float* row = Mw + (size_t)c*160;
#pragma unroll
  for (int k = 0; k < 64; k += 4){
    float4 a = *(const float4*)(row + k);
    float4 b = *(const float4*)(row + 64 + k);
    ws[k]=a.x; ws[k+1]=a.y; ws[k+2]=a.z; ws[k+3]=a.w;
    wd[k]=b.x; wd[k+1]=b.y; wd[k+2]=b.z; wd[k+3]=b.w;
  }
  float bias = Mb[c];
  for (int n = blockIdx.x; n < N; n += gridDim.x){
    const float* h = nf + (size_t)n*256 + t*64;
    float sa = 0.f, sb = 0.f;
#pragma unroll
    for (int k = 0; k < 64; k += 4){
      float4 h4 = *(const float4*)(h + k);
      sa = fmaf(ws[k], h4.x, sa);  sb = fmaf(wd[k], h4.x, sb);
      sa = fmaf(ws[k+1], h4.y, sa); sb = fmaf(wd[k+1], h4.y, sb);
      sa = fmaf(ws[k+2], h4.z, sa); sb = fmaf(wd[k+2], h4.z, sb);
      sa = fmaf(ws[k+3], h4.w, sa); sb = fmaf(wd[k+3], h4.w, sb);
    }
    A[(size_t)n*256 + c] = sa;
    B[(size_t)n*256 + c] = sb + bias;
  }
}

// ---------- per-node aggregation (block = node, thread = channel) ----------

__global__ __launch_bounds__(256) void k_agg(const int* __restrict__ offs, const int* __restrict__ elist,
                                             const int* __restrict__ srcv, const float* __restrict__ efeat,
                                             const float* __restrict__ A, const float* __restrict__ B,
                                             const float* __restrict__ Mw,
                                             float* __restrict__ agg, float* __restrict__ sc, int N){
  int c = threadIdx.x;
  float4 wef[8];
  const float* wrow = Mw + (size_t)c*160 + 128;
#pragma unroll
  for (int q = 0; q < 8; ++q) wef[q] = *(const float4*)(wrow + 4*q);

  for (int n = blockIdx.x; n < N; n += gridDim.x){
    int o0 = __builtin_amdgcn_readfirstlane(offs[n]);
    int o1 = __builtin_amdgcn_readfirstlane(offs[n+1]);
    int cnt = o1 - o0;
    float b0 = B[(size_t)n*256 + c];
    float s = 0.f, ss = 0.f, mx = -__builtin_huge_valf(), mn = __builtin_huge_valf();
    for (int i = 0; i < cnt; ++i){
      int e    = __builtin_amdgcn_readfirstlane(elist[o0 + i]);
      int sidx = __builtin_amdgcn_readfirstlane(srcv[e]);
      const float* ef = efeat + (size_t)e*32;
      float m = b0 + A[(size_t)sidx*256 + c];
#pragma unroll
      for (int q = 0; q < 8; ++q){
        float4 e4 = *(const float4*)(ef + 4*q);
        m = fmaf(e4.x, wef[q].x, m);
        m = fmaf(e4.y, wef[q].y, m);
        m = fmaf(e4.z, wef[q].z, m);
        m = fmaf(e4.w, wef[q].w, m);
      }
      s += m;
      ss = fmaf(m, m, ss);
      mx = fmaxf(mx, m);
      mn = fminf(mn, m);
    }
    float deg  = (float)cnt;
    float degc = fmaxf(deg, 1.f);
    float inv  = 1.f / degc;
    float mean = s * inv;
    float var  = fmaxf(ss * inv - mean*mean, 0.f);
    float sd   = sqrtf(var + 1e-30f);
    if (cnt == 0){ mx = 0.f; mn = 0.f; }
    float* ar = agg + (size_t)n*1024 + (size_t)(c >> 6)*256 + (c & 63);
    ar[0]   = mean;
    ar[64]  = mx;
    ar[128] = mn;
    ar[192] = sd;
    if (c == 0){
      float logd = logf(deg + 1.f);
      sc[(size_t)n*2]     = logd * (1.f / DELTA_);
      sc[(size_t)n*2 + 1] = (cnt > 0) ? (DELTA_ / fmaxf(logd, 1e-12f)) : 0.f;
    }
  }
}

// ---------- U GEMM: lane = node, wave = tower, thread owns 64 out channels ----------

#define ROW_FMA(WPTR, AV) { const float* __wr = (WPTR); \
  _Pragma("unroll") for (int c2 = 0; c2 < 64; ++c2) acc[c2] = fmaf(__wr[c2], (AV), acc[c2]); }

__global__ __launch_bounds__(256) void k_u(const float* __restrict__ nf, const float* __restrict__ agg,
                                           const float* __restrict__ sc, const float* __restrict__ UwT,
                                           const float* __restrict__ Ub, float* __restrict__ uout, int N){
  int lane = threadIdx.x & 63;
  int t = __builtin_amdgcn_readfirstlane(threadIdx.x >> 6);
  int n = blockIdx.x*64 + lane;
  bool valid = (n < N);
  if (!valid) n = N - 1;
  float amp = sc[(size_t)n*2];
  float att = sc[(size_t)n*2 + 1];
  const float* wt = UwT + (size_t)t*832*64;
  float acc[64];
#pragma unroll
  for (int c2 = 0; c2 < 64; ++c2) acc[c2] = 0.f;

  // h part: k in [0,64)
  const float* h = nf + (size_t)n*256 + t*64;
#pragma unroll 1
  for (int q = 0; q < 16; ++q){
    float4 a4 = *(const float4*)(h + 4*q);
    const float* w0 = wt + (size_t)(4*q)*64;
    ROW_FMA(w0,        a4.x);
    ROW_FMA(w0 + 64,   a4.y);
    ROW_FMA(w0 + 128,  a4.z);
    ROW_FMA(w0 + 192,  a4.w);
  }
  // agg / agg*amp / agg*att parts: k in [64,832)
  const float* ag = agg + (size_t)n*1024 + t*256;
#pragma unroll 1
  for (int q = 0; q < 64; ++q){
    float4 a4 = *(const float4*)(ag + 4*q);
    float ax = a4.x*amp, ay = a4.y*amp, az = a4.z*amp, aw = a4.w*amp;
    float tx = a4.x*att, ty = a4.y*att, tz = a4.z*att, tw = a4.w*att;
    const float* wA  = wt + (size_t)(64  + 4*q)*64;
    const float* wAA = wt + (size_t)(320 + 4*q)*64;
    const float* wAT = wt + (size_t)(576 + 4*q)*64;
    ROW_FMA(wA,         a4.x); ROW_FMA(wA + 64,   a4.y);
    ROW_FMA(wA + 128,   a4.z); ROW_FMA(wA + 192,  a4.w);
    ROW_FMA(wAA,        ax);   ROW_FMA(wAA + 64,  ay);
    ROW_FMA(wAA + 128,  az);   ROW_FMA(wAA + 192, aw);
    ROW_FMA(wAT,        tx);   ROW_FMA(wAT + 64,  ty);
    ROW_FMA(wAT + 128,  tz);   ROW_FMA(wAT + 192, tw);
  }
  if (valid){
    float* up = uout + (size_t)n*256 + t*64;
    const float* ub = Ub + t*64;
#pragma unroll
    for (int c2 = 0; c2 < 64; c2 += 4){
      float4 v;
      v.x = acc[c2]   + ub[c2];
      v.y = acc[c2+1] + ub[c2+1];
      v.z = acc[c2+2] + ub[c2+2];
      v.w = acc[c2+3] + ub[c2+3];
      *(float4*)(up + c2) = v;
    }
  }
}

// ---------- batchnorm stats ----------

__global__ __launch_bounds__(256) void k_bnstat(const float* __restrict__ u, float* __restrict__ stat, int N){
  int c = threadIdx.x;
  float s = 0.f, ss = 0.f;
  for (int n = blockIdx.x; n < N; n += gridDim.x){
    float v = u[(size_t)n*256 + c];
    s += v;
    ss = fmaf(v, v, ss);
  }
  atomicAdd(&stat[c], s);
  atomicAdd(&stat[256 + c], ss);
}

__global__ __launch_bounds__(256) void k_bnfin(const float* __restrict__ stat, const float* __restrict__ gam,
                                               const float* __restrict__ bet, float* __restrict__ bnsc, int N){
  int c = threadIdx.x;
  float invN = 1.f / (float)N;
  float mu  = stat[c] * invN;
  float ex2 = stat[256 + c] * invN;
  float var = fmaxf(ex2 - mu*mu, 0.f);
  float inv = 1.f / sqrtf(var + 1e-5f);
  float scale = gam[c] * inv;
  bnsc[c]       = scale;
  bnsc[256 + c] = bet[c] - mu*scale;
}

// ---------- mix GEMM + leaky + residual + relu (in-place on uo) ----------

__global__ __launch_bounds__(256) void k_mix(float* uo, const float* __restrict__ bnsc,
                                             const float* __restrict__ mixT, const float* __restrict__ mixb,
                                             const float* __restrict__ nf, int N){
  int lane = threadIdx.x & 63;
  int w = __builtin_amdgcn_readfirstlane(threadIdx.x >> 6);
  int n = blockIdx.x*64 + lane;
  bool valid = (n < N);
  if (!valid) n = N - 1;
  float acc[64];
#pragma unroll
  for (int c2 = 0; c2 < 64; ++c2) acc[c2] = 0.f;
  const float* ur = uo + (size_t)n*256;
#pragma unroll 1
  for (int q = 0; q < 64; ++q){
    float4 u4 = *(const float4*)(ur + 4*q);
    float4 s4 = *(const float4*)(bnsc + 4*q);
    float4 h4 = *(const float4*)(bnsc + 256 + 4*q);
    float a0 = fmaf(u4.x, s4.x, h4.x);
    float a1 = fmaf(u4.y, s4.y, h4.y);
    float a2 = fmaf(u4.z, s4.z, h4.z);
    float a3 = fmaf(u4.w, s4.w, h4.w);
    const float* w0 = mixT + (size_t)(4*q)*256 + w*64;
    ROW_FMA(w0,       a0);
    ROW_FMA(w0 + 256, a1);
    ROW_FMA(w0 + 512, a2);
    ROW_FMA(w0 + 768, a3);
  }
  __syncthreads();   // all waves done READING u rows before any wave overwrites them
  if (valid){
    int j0 = w*64;
    const float* r = nf + (size_t)n*256 + j0;
    float* op = uo + (size_t)n*256 + j0;
#pragma unroll
    for (int c2 = 0; c2 < 64; c2 += 4){
      float4 v;
      float m0 = acc[c2]   + mixb[j0 + c2];
      float m1 = acc[c2+1] + mixb[j0 + c2 + 1];
      float m2 = acc[c2+2] + mixb[j0 + c2 + 2];
      float m3 = acc[c2+3] + mixb[j0 + c2 + 3];
      m0 = (m0 > 0.f) ? m0 : 0.01f*m0;
      m1 = (m1 > 0.f) ? m1 : 0.01f*m1;
      m2 = (m2 > 0.f) ? m2 : 0.01f*m2;
      m3 = (m3 > 0.f) ? m3 : 0.01f*m3;
      v.x = fmaxf(m0 + r[c2],   0.f);
      v.y = fmaxf(m1 + r[c2+1], 0.f);
      v.z = fmaxf(m2 + r[c2+2], 0.f);
      v.w = fmaxf(m3 + r[c2+3], 0.f);
      *(float4*)(op + c2) = v;
    }
  }
}

// ---------- host launcher ----------

extern "C" void kernel_launch(void* const* d_in, const int* in_sizes, int n_in,
                              void* d_out, int out_size, void* d_ws, size_t ws_size,
                              hipStream_t stream){
  const float* nf   = (const float*)d_in[0];
  const float* ef   = (const float*)d_in[1];
  const int*   srcv = (const int*)  d_in[2];
  const int*   dstv = (const int*)  d_in[3];
  const float* Mw   = (const float*)d_in[4];
  const float* Mb   = (const float*)d_in[5];
  const float* Uw   = (const float*)d_in[6];
  const float* Ub   = (const float*)d_in[7];
  const float* gam  = (const float*)d_in[8];
  const float* bet  = (const float*)d_in[9];
  const float* mixw = (const float*)d_in[10];
  const float* mixb = (const float*)d_in[11];
  int N = in_sizes[0] / 256;
  int E = in_sizes[2];
  float* out = (float*)d_out;

  char* wp = (char*)d_ws;
  auto alloc = [&](size_t bytes){
    char* p = wp;
    wp += (bytes + 1023) & ~(size_t)1023;
    return (void*)p;
  };
  int*   cnt   = (int*)  alloc((size_t)N*4);
  int*   offs  = (int*)  alloc((size_t)(N+1)*4);
  int*   cur   = (int*)  alloc((size_t)N*4);
  int*   bsum  = (int*)  alloc(256*4);
  int*   elist = (int*)  alloc((size_t)E*4);
  float* A     = (float*)alloc((size_t)N*256*4);
  float* B     = (float*)alloc((size_t)N*256*4);
  float* agg   = (float*)alloc((size_t)N*1024*4);
  float* sc    = (float*)alloc((size_t)N*2*4);
  float* stat  = (float*)alloc(512*4);
  float* bnsc  = (float*)alloc(512*4);
  float* UwT   = (float*)alloc((size_t)4*832*64*4);
  float* mixT  = (float*)alloc((size_t)256*256*4);

  hipMemsetAsync(cnt,  0, (size_t)N*4,  stream);
  hipMemsetAsync(cur,  0, (size_t)N*4,  stream);
  hipMemsetAsync(stat, 0, 512*4,        stream);

  k_tU  <<<(4*832*64 + 255)/256, 256, 0, stream>>>(Uw, UwT);
  k_tM  <<<256, 256, 0, stream>>>(mixw, mixT);
  k_hist<<<(E + 255)/256, 256, 0, stream>>>(dstv, cnt, E);
  k_ab  <<<1024, 256, 0, stream>>>(nf, Mw, Mb, A, B, N);

  int NB = (N + 255)/256;
  k_scan1<<<NB, 256, 0, stream>>>(cnt, offs, bsum, N);
  k_scan2<<<1, 256, 0, stream>>>(bsum, NB);
  k_scan3<<<NB, 256, 0, stream>>>(offs, bsum, N, E);
  k_fill <<<(E + 255)/256, 256, 0, stream>>>(dstv, offs, cur, elist, E);

  k_agg<<<1920, 256, 0, stream>>>(offs, elist, srcv, ef, A, B, Mw, agg, sc, N);
  k_u  <<<(N + 63)/64, 256, 0, stream>>>(nf, agg, sc, UwT, Ub, out, N);
  k_bnstat<<<256, 256, 0, stream>>>(out, stat, N);
  k_bnfin <<<1, 256, 0, stream>>>(stat, gam, bet, bnsc, N);
  k_mix<<<(N + 63)/64, 256, 0, stream>>>(out, bnsc, mixT, mixb, nf, N);
}

// Round 2
// 771.268 us; speedup vs baseline: 1.1519x; 1.1519x over previous
//
#include <hip/hip_runtime.h>
#include <math.h>

constexpr float DELTA_ = 2.5f;
#define BN_BLOCKS 512

// ---------- small prep kernels ----------

__global__ __launch_bounds__(256) void k_tU(const float* __restrict__ Uw, float* __restrict__ UwT){
  int i = blockIdx.x*256 + threadIdx.x;            // i = (t*832 + k)*64 + o
  if (i >= 4*832*64) return;
  int o = i & 63;
  int k = (i >> 6) % 832;
  int t = (i >> 6) / 832;
  UwT[i] = Uw[(size_t)(t*64 + o)*832 + k];
}

__global__ __launch_bounds__(256) void k_tM(const float* __restrict__ Mx, float* __restrict__ MxT){
  int i = blockIdx.x*256 + threadIdx.x;            // i = k*256 + j
  if (i >= 256*256) return;
  int j = i & 255, k = i >> 8;
  MxT[i] = Mx[j*256 + k];
}

__global__ __launch_bounds__(256) void k_hist(const int* __restrict__ dstv, int* __restrict__ cnt, int E){
  int e = blockIdx.x*256 + threadIdx.x;
  if (e < E) atomicAdd(&cnt[dstv[e]], 1);
}

__global__ __launch_bounds__(256) void k_scan1(const int* __restrict__ cnt, int* __restrict__ offs,
                                               int* __restrict__ bsum, int N){
  __shared__ int lds[256];
  int i = threadIdx.x;
  int g = blockIdx.x*256 + i;
  int v = (g < N) ? cnt[g] : 0;
  int acc = v;
  lds[i] = acc; __syncthreads();
  for (int s = 1; s < 256; s <<= 1){
    int t = (i >= s) ? lds[i - s] : 0;
    __syncthreads();
    acc += t; lds[i] = acc;
    __syncthreads();
  }
  if (g < N) offs[g] = acc - v;                    // exclusive within block
  if (i == 255) bsum[blockIdx.x] = acc;
}

__global__ __launch_bounds__(256) void k_scan2(int* __restrict__ bsum, int NB){
  __shared__ int lds[256];
  int i = threadIdx.x;
  int v = (i < NB) ? bsum[i] : 0;
  int acc = v;
  lds[i] = acc; __syncthreads();
  for (int s = 1; s < 256; s <<= 1){
    int t = (i >= s) ? lds[i - s] : 0;
    __syncthreads();
    acc += t; lds[i] = acc;
    __syncthreads();
  }
  if (i < NB) bsum[i] = acc - v;                   // exclusive block offsets
}

__global__ __launch_bounds__(256) void k_scan3(int* __restrict__ offs, const int* __restrict__ bsum, int N, int E){
  int g = blockIdx.x*256 + threadIdx.x;
  if (g < N) offs[g] += bsum[blockIdx.x];
  if (g == 0) offs[N] = E;
}

__global__ __launch_bounds__(256) void k_fill(const int* __restrict__ dstv, const int* __restrict__ offs,
                                              int* __restrict__ cur, int* __restrict__ elist, int E){
  int e = blockIdx.x*256 + threadIdx.x;
  if (e < E){
    int d = dstv[e];
    elist[offs[d] + atomicAdd(&cur[d], 1)] = e;
  }
}

// ---------- A = W_src*h, B = W_dst*h + M_b (per node) ----------

__global__ __launch_bounds__(256) void k_ab(const float* __restrict__ nf, const float* __restrict__ Mw,
                                            const float* __restrict__ Mb,
                                            float* __restrict__ A, float* __restrict__ B, int N){
  int c = threadIdx.x;
  int t = __builtin_amdgcn_readfirstlane(threadIdx.x >> 6);
  float ws[64], wd[64];
  const float* row = Mw + (size_t)c*160;
#pragma unroll
  for (int k = 0; k < 64; k += 4){
    float4 a = *(const float4*)(row + k);
    float4 b = *(const float4*)(row + 64 + k);
    ws[k]=a.x; ws[k+1]=a.y; ws[k+2]=a.z; ws[k+3]=a.w;
    wd[k]=b.x; wd[k+1]=b.y; wd[k+2]=b.z; wd[k+3]=b.w;
  }
  float bias = Mb[c];
  for (int n = blockIdx.x; n < N; n += gridDim.x){
    const float* h = nf + (size_t)n*256 + t*64;
    float sa = 0.f, sb = 0.f;
#pragma unroll
    for (int k = 0; k < 64; k += 4){
      float4 h4 = *(const float4*)(h + k);
      sa = fmaf(ws[k], h4.x, sa);  sb = fmaf(wd[k], h4.x, sb);
      sa = fmaf(ws[k+1], h4.y, sa); sb = fmaf(wd[k+1], h4.y, sb);
      sa = fmaf(ws[k+2], h4.z, sa); sb = fmaf(wd[k+2], h4.z, sb);
      sa = fmaf(ws[k+3], h4.w, sa); sb = fmaf(wd[k+3], h4.w, sb);
    }
    A[(size_t)n*256 + c] = sa;
    B[(size_t)n*256 + c] = sb + bias;
  }
}

// ---------- per-node aggregation: block = node, thread = channel, 4-edge ILP ----------

__global__ __launch_bounds__(256) void k_agg(const int* __restrict__ offs, const int* __restrict__ elist,
                                             const int* __restrict__ srcv, const float* __restrict__ efeat,
                                             const float* __restrict__ A, const float* __restrict__ B,
                                             const float* __restrict__ Mw,
                                             float* __restrict__ agg, float* __restrict__ sc, int N){
  int c = threadIdx.x;
  float4 wef[8];
  const float* wrow = Mw + (size_t)c*160 + 128;
#pragma unroll
  for (int q = 0; q < 8; ++q) wef[q] = *(const float4*)(wrow + 4*q);

  int n = blockIdx.x;
  if (n >= N) return;
  int o0 = __builtin_amdgcn_readfirstlane(offs[n]);
  int o1 = __builtin_amdgcn_readfirstlane(offs[n+1]);
  int cnt = o1 - o0;
  float b0 = B[(size_t)n*256 + c];
  float s = 0.f, ss = 0.f, mx = -__builtin_huge_valf(), mn = __builtin_huge_valf();

  int i = 0;
  for (; i + 4 <= cnt; i += 4){
    // hoist all index loads (wave-uniform -> s_load) and A-gathers: 4 in flight
    int e0 = __builtin_amdgcn_readfirstlane(elist[o0+i+0]);
    int e1 = __builtin_amdgcn_readfirstlane(elist[o0+i+1]);
    int e2 = __builtin_amdgcn_readfirstlane(elist[o0+i+2]);
    int e3 = __builtin_amdgcn_readfirstlane(elist[o0+i+3]);
    int s0 = __builtin_amdgcn_readfirstlane(srcv[e0]);
    int s1 = __builtin_amdgcn_readfirstlane(srcv[e1]);
    int s2 = __builtin_amdgcn_readfirstlane(srcv[e2]);
    int s3 = __builtin_amdgcn_readfirstlane(srcv[e3]);
    float a0 = A[(size_t)s0*256 + c];
    float a1 = A[(size_t)s1*256 + c];
    float a2 = A[(size_t)s2*256 + c];
    float a3 = A[(size_t)s3*256 + c];
    const float* p0 = efeat + (size_t)e0*32;
    const float* p1 = efeat + (size_t)e1*32;
    const float* p2 = efeat + (size_t)e2*32;
    const float* p3 = efeat + (size_t)e3*32;
    float m0 = b0 + a0;
    float m1 = b0 + a1;
    float m2 = b0 + a2;
    float m3 = b0 + a3;
#pragma unroll
    for (int q = 0; q < 8; ++q){
      float4 f0 = *(const float4*)(p0 + 4*q);
      float4 f1 = *(const float4*)(p1 + 4*q);
      float4 f2 = *(const float4*)(p2 + 4*q);
      float4 f3 = *(const float4*)(p3 + 4*q);
      m0 = fmaf(f0.x, wef[q].x, m0); m0 = fmaf(f0.y, wef[q].y, m0);
      m0 = fmaf(f0.z, wef[q].z, m0); m0 = fmaf(f0.w, wef[q].w, m0);
      m1 = fmaf(f1.x, wef[q].x, m1); m1 = fmaf(f1.y, wef[q].y, m1);
      m1 = fmaf(f1.z, wef[q].z, m1); m1 = fmaf(f1.w, wef[q].w, m1);
      m2 = fmaf(f2.x, wef[q].x, m2); m2 = fmaf(f2.y, wef[q].y, m2);
      m2 = fmaf(f2.z, wef[q].z, m2); m2 = fmaf(f2.w, wef[q].w, m2);
      m3 = fmaf(f3.x, wef[q].x, m3); m3 = fmaf(f3.y, wef[q].y, m3);
      m3 = fmaf(f3.z, wef[q].z, m3); m3 = fmaf(f3.w, wef[q].w, m3);
    }
    s += m0; s += m1; s += m2; s += m3;
    ss = fmaf(m0, m0, ss); ss = fmaf(m1, m1, ss);
    ss = fmaf(m2, m2, ss); ss = fmaf(m3, m3, ss);
    mx = fmaxf(mx, fmaxf(fmaxf(m0, m1), fmaxf(m2, m3)));
    mn = fminf(mn, fminf(fminf(m0, m1), fminf(m2, m3)));
  }
  for (; i < cnt; ++i){
    int e    = __builtin_amdgcn_readfirstlane(elist[o0 + i]);
    int sidx = __builtin_amdgcn_readfirstlane(srcv[e]);
    const float* ef = efeat + (size_t)e*32;
    float m = b0 + A[(size_t)sidx*256 + c];
#pragma unroll
    for (int q = 0; q < 8; ++q){
      float4 e4 = *(const float4*)(ef + 4*q);
      m = fmaf(e4.x, wef[q].x, m);
      m = fmaf(e4.y, wef[q].y, m);
      m = fmaf(e4.z, wef[q].z, m);
      m = fmaf(e4.w, wef[q].w, m);
    }
    s += m;
    ss = fmaf(m, m, ss);
    mx = fmaxf(mx, m);
    mn = fminf(mn, m);
  }

  float deg  = (float)cnt;
  float degc = fmaxf(deg, 1.f);
  float inv  = 1.f / degc;
  float mean = s * inv;
  float var  = fmaxf(ss * inv - mean*mean, 0.f);
  float sd   = sqrtf(var + 1e-30f);
  if (cnt == 0){ mx = 0.f; mn = 0.f; }
  float* ar = agg + (size_t)n*1024 + (size_t)(c >> 6)*256 + (c & 63);
  ar[0]   = mean;
  ar[64]  = mx;
  ar[128] = mn;
  ar[192] = sd;
  if (c == 0){
    float logd = logf(deg + 1.f);
    sc[(size_t)n*2]     = logd * (1.f / DELTA_);
    sc[(size_t)n*2 + 1] = (cnt > 0) ? (DELTA_ / fmaxf(logd, 1e-12f)) : 0.f;
  }
}

// ---------- U GEMM: lane = node, 8 waves = (tower, out-half), thread owns 32 out ----------

#define ROW_FMA32(WPTR, AV) { const float* __wr = (WPTR); \
  _Pragma("unroll") for (int c2 = 0; c2 < 32; ++c2) acc[c2] = fmaf(__wr[c2], (AV), acc[c2]); }

__global__ __launch_bounds__(512) void k_u(const float* __restrict__ nf, const float* __restrict__ agg,
                                           const float* __restrict__ sc, const float* __restrict__ UwT,
                                           const float* __restrict__ Ub, float* __restrict__ uout, int N){
  int lane = threadIdx.x & 63;
  int wv   = threadIdx.x >> 6;                       // 0..7
  int t  = __builtin_amdgcn_readfirstlane(wv >> 1);  // tower
  int hf = __builtin_amdgcn_readfirstlane(wv & 1);   // out-channel half
  int n = blockIdx.x*64 + lane;
  bool valid = (n < N);
  if (!valid) n = N - 1;
  float amp = sc[(size_t)n*2];
  float att = sc[(size_t)n*2 + 1];
  const float* wt = UwT + (size_t)t*832*64 + hf*32;
  float acc[32];
#pragma unroll
  for (int c2 = 0; c2 < 32; ++c2) acc[c2] = 0.f;

  // h part: k in [0,64)
  const float* h = nf + (size_t)n*256 + t*64;
#pragma unroll 1
  for (int q = 0; q < 16; ++q){
    float4 a4 = *(const float4*)(h + 4*q);
    const float* w0 = wt + (size_t)(4*q)*64;
    ROW_FMA32(w0,        a4.x);
    ROW_FMA32(w0 + 64,   a4.y);
    ROW_FMA32(w0 + 128,  a4.z);
    ROW_FMA32(w0 + 192,  a4.w);
  }
  // agg / agg*amp / agg*att parts: k in [64,832)
  const float* ag = agg + (size_t)n*1024 + t*256;
#pragma unroll 1
  for (int q = 0; q < 64; ++q){
    float4 a4 = *(const float4*)(ag + 4*q);
    float ax = a4.x*amp, ay = a4.y*amp, az = a4.z*amp, aw = a4.w*amp;
    float tx = a4.x*att, ty = a4.y*att, tz = a4.z*att, tw = a4.w*att;
    const float* wA  = wt + (size_t)(64  + 4*q)*64;
    const float* wAA = wt + (size_t)(320 + 4*q)*64;
    const float* wAT = wt + (size_t)(576 + 4*q)*64;
    ROW_FMA32(wA,         a4.x); ROW_FMA32(wA + 64,   a4.y);
    ROW_FMA32(wA + 128,   a4.z); ROW_FMA32(wA + 192,  a4.w);
    ROW_FMA32(wAA,        ax);   ROW_FMA32(wAA + 64,  ay);
    ROW_FMA32(wAA + 128,  az);   ROW_FMA32(wAA + 192, aw);
    ROW_FMA32(wAT,        tx);   ROW_FMA32(wAT + 64,  ty);
    ROW_FMA32(wAT + 128,  tz);   ROW_FMA32(wAT + 192, tw);
  }
  if (valid){
    float* up = uout + (size_t)n*256 + t*64 + hf*32;
    const float* ub = Ub + t*64 + hf*32;
#pragma unroll
    for (int c2 = 0; c2 < 32; c2 += 4){
      float4 v;
      v.x = acc[c2]   + ub[c2];
      v.y = acc[c2+1] + ub[c2+1];
      v.z = acc[c2+2] + ub[c2+2];
      v.w = acc[c2+3] + ub[c2+3];
      *(float4*)(up + c2) = v;
    }
  }
}

// ---------- batchnorm stats (deterministic: fixed partials, no float atomics) ----------

__global__ __launch_bounds__(256) void k_bnstat(const float* __restrict__ u, float* __restrict__ part, int N){
  int c = threadIdx.x;
  int b = blockIdx.x;
  float s = 0.f, ss = 0.f;
  for (int n = b; n < N; n += gridDim.x){
    float v = u[(size_t)n*256 + c];
    s += v;
    ss = fmaf(v, v, ss);
  }
  part[(size_t)b*512 + c]       = s;
  part[(size_t)b*512 + 256 + c] = ss;
}

__global__ __launch_bounds__(256) void k_bnfin(const float* __restrict__ part, const float* __restrict__ gam,
                                               const float* __restrict__ bet, float* __restrict__ bnsc, int N){
  int c = threadIdx.x;
  float s = 0.f, ss = 0.f;
  for (int b = 0; b < BN_BLOCKS; ++b){
    s  += part[(size_t)b*512 + c];
    ss += part[(size_t)b*512 + 256 + c];
  }
  float invN = 1.f / (float)N;
  float mu  = s * invN;
  float ex2 = ss * invN;
  float var = fmaxf(ex2 - mu*mu, 0.f);
  float inv = 1.f / sqrtf(var + 1e-5f);
  float scale = gam[c] * inv;
  bnsc[c]       = scale;
  bnsc[256 + c] = bet[c] - mu*scale;
}

// ---------- mix GEMM + leaky + residual + relu (in-place on uo) ----------

#define ROW_FMA(WPTR, AV) { const float* __wr = (WPTR); \
  _Pragma("unroll") for (int c2 = 0; c2 < 64; ++c2) acc[c2] = fmaf(__wr[c2], (AV), acc[c2]); }

__global__ __launch_bounds__(256) void k_mix(float* uo, const float* __restrict__ bnsc,
                                             const float* __restrict__ mixT, const float* __restrict__ mixb,
                                             const float* __restrict__ nf, int N){
  int lane = threadIdx.x & 63;
  int w = __builtin_amdgcn_readfirstlane(threadIdx.x >> 6);
  int n = blockIdx.x*64 + lane;
  bool valid = (n < N);
  if (!valid) n = N - 1;
  float acc[64];
#pragma unroll
  for (int c2 = 0; c2 < 64; ++c2) acc[c2] = 0.f;
  const float* ur = uo + (size_t)n*256;
#pragma unroll 1
  for (int q = 0; q < 64; ++q){
    float4 u4 = *(const float4*)(ur + 4*q);
    float4 s4 = *(const float4*)(bnsc + 4*q);
    float4 h4 = *(const float4*)(bnsc + 256 + 4*q);
    float a0 = fmaf(u4.x, s4.x, h4.x);
    float a1 = fmaf(u4.y, s4.y, h4.y);
    float a2 = fmaf(u4.z, s4.z, h4.z);
    float a3 = fmaf(u4.w, s4.w, h4.w);
    const float* w0 = mixT + (size_t)(4*q)*256 + w*64;
    ROW_FMA(w0,       a0);
    ROW_FMA(w0 + 256, a1);
    ROW_FMA(w0 + 512, a2);
    ROW_FMA(w0 + 768, a3);
  }
  __syncthreads();   // all waves done READING u rows before any wave overwrites them
  if (valid){
    int j0 = w*64;
    const float* r = nf + (size_t)n*256 + j0;
    float* op = uo + (size_t)n*256 + j0;
#pragma unroll
    for (int c2 = 0; c2 < 64; c2 += 4){
      float4 v;
      float m0 = acc[c2]   + mixb[j0 + c2];
      float m1 = acc[c2+1] + mixb[j0 + c2 + 1];
      float m2 = acc[c2+2] + mixb[j0 + c2 + 2];
      float m3 = acc[c2+3] + mixb[j0 + c2 + 3];
      m0 = (m0 > 0.f) ? m0 : 0.01f*m0;
      m1 = (m1 > 0.f) ? m1 : 0.01f*m1;
      m2 = (m2 > 0.f) ? m2 : 0.01f*m2;
      m3 = (m3 > 0.f) ? m3 : 0.01f*m3;
      v.x = fmaxf(m0 + r[c2],   0.f);
      v.y = fmaxf(m1 + r[c2+1], 0.f);
      v.z = fmaxf(m2 + r[c2+2], 0.f);
      v.w = fmaxf(m3 + r[c2+3], 0.f);
      *(float4*)(op + c2) = v;
    }
  }
}

// ---------- host launcher ----------

extern "C" void kernel_launch(void* const* d_in, const int* in_sizes, int n_in,
                              void* d_out, int out_size, void* d_ws, size_t ws_size,
                              hipStream_t stream){
  const float* nf   = (const float*)d_in[0];
  const float* ef   = (const float*)d_in[1];
  const int*   srcv = (const int*)  d_in[2];
  const int*   dstv = (const int*)  d_in[3];
  const float* Mw   = (const float*)d_in[4];
  const float* Mb   = (const float*)d_in[5];
  const float* Uw   = (const float*)d_in[6];
  const float* Ub   = (const float*)d_in[7];
  const float* gam  = (const float*)d_in[8];
  const float* bet  = (const float*)d_in[9];
  const float* mixw = (const float*)d_in[10];
  const float* mixb = (const float*)d_in[11];
  int N = in_sizes[0] / 256;
  int E = in_sizes[2];
  float* out = (float*)d_out;

  char* wp = (char*)d_ws;
  auto alloc = [&](size_t bytes){
    char* p = wp;
    wp += (bytes + 1023) & ~(size_t)1023;
    return (void*)p;
  };
  int*   cnt   = (int*)  alloc((size_t)N*4);
  int*   offs  = (int*)  alloc((size_t)(N+1)*4);
  int*   cur   = (int*)  alloc((size_t)N*4);
  int*   bsum  = (int*)  alloc(256*4);
  int*   elist = (int*)  alloc((size_t)E*4);
  float* A     = (float*)alloc((size_t)N*256*4);
  float* B     = (float*)alloc((size_t)N*256*4);
  float* agg   = (float*)alloc((size_t)N*1024*4);
  float* sc    = (float*)alloc((size_t)N*2*4);
  float* part  = (float*)alloc((size_t)BN_BLOCKS*512*4);
  float* bnsc  = (float*)alloc(512*4);
  float* UwT   = (float*)alloc((size_t)4*832*64*4);
  float* mixT  = (float*)alloc((size_t)256*256*4);

  hipMemsetAsync(cnt,  0, (size_t)N*4,  stream);
  hipMemsetAsync(cur,  0, (size_t)N*4,  stream);

  k_tU  <<<(4*832*64 + 255)/256, 256, 0, stream>>>(Uw, UwT);
  k_tM  <<<256, 256, 0, stream>>>(mixw, mixT);
  k_hist<<<(E + 255)/256, 256, 0, stream>>>(dstv, cnt, E);
  k_ab  <<<2048, 256, 0, stream>>>(nf, Mw, Mb, A, B, N);

  int NB = (N + 255)/256;
  k_scan1<<<NB, 256, 0, stream>>>(cnt, offs, bsum, N);
  k_scan2<<<1, 256, 0, stream>>>(bsum, NB);
  k_scan3<<<NB, 256, 0, stream>>>(offs, bsum, N, E);
  k_fill <<<(E + 255)/256, 256, 0, stream>>>(dstv, offs, cur, elist, E);

  k_agg<<<N, 256, 0, stream>>>(offs, elist, srcv, ef, A, B, Mw, agg, sc, N);
  k_u  <<<(N + 63)/64, 512, 0, stream>>>(nf, agg, sc, UwT, Ub, out, N);
  k_bnstat<<<BN_BLOCKS, 256, 0, stream>>>(out, part, N);
  k_bnfin <<<1, 256, 0, stream>>>(part, gam, bet, bnsc, N);
  k_mix<<<(N + 63)/64, 256, 0, stream>>>(out, bnsc, mixT, mixb, nf, N);
}